// Round 9
// baseline (354.021 us; speedup 1.0000x reference)
//
#include <hip/hip_runtime.h>
#include <math.h>

#define N_C 1024
#define M_F 64
#define B_R 32768
#define R_B 16       // sample rows per block
#define LDX 132      // padded fp32 leading dim for X in LDS
#define PF  2        // B prefetch ring depth (tiles); PF=2 fits the (256,4) reg cap

typedef short bf16x8 __attribute__((ext_vector_type(8)));
typedef float f32x4 __attribute__((ext_vector_type(4)));
typedef unsigned int uint4v __attribute__((ext_vector_type(4)));

__device__ __forceinline__ short f2bf(float x) {
  unsigned b = __float_as_uint(x);
  b += 0x7fffu + ((b >> 16) & 1u);   // RTNE (finite inputs only)
  return (short)(b >> 16);
}
__device__ __forceinline__ float bf2f(short h) {
  return __uint_as_float(((unsigned)(unsigned short)h) << 16);
}

// Exact truncation-based 3-way split (h+m+l == x exactly); bit-ops only.
__device__ __forceinline__ void split3(const float* f, bf16x8& h, bf16x8& m, bf16x8& l) {
  uint4v hp, mp, lp;
#pragma unroll
  for (int i = 0; i < 4; ++i) {
    const unsigned b0 = __float_as_uint(f[2 * i]);
    const unsigned b1 = __float_as_uint(f[2 * i + 1]);
    const unsigned h0 = b0 & 0xFFFF0000u, h1 = b1 & 0xFFFF0000u;
    const float r0 = f[2 * i] - __uint_as_float(h0);       // exact
    const float r1 = f[2 * i + 1] - __uint_as_float(h1);   // exact
    hp[i] = (b0 >> 16) | h1;
    const unsigned rb0 = __float_as_uint(r0), rb1 = __float_as_uint(r1);
    const unsigned m0 = rb0 & 0xFFFF0000u, m1 = rb1 & 0xFFFF0000u;
    const float s0 = r0 - __uint_as_float(m0);             // exact
    const float s1 = r1 - __uint_as_float(m1);             // exact
    mp[i] = (rb0 >> 16) | m1;
    lp[i] = (__float_as_uint(s0) >> 16) | (__float_as_uint(s1) & 0xFFFF0000u);
  }
  h = __builtin_bit_cast(bf16x8, hp);
  m = __builtin_bit_cast(bf16x8, mp);
  l = __builtin_bit_cast(bf16x8, lp);
}

__global__ void logprior_kernel(const float* __restrict__ lm, float* __restrict__ lp) {
  __shared__ float red[256];
  const int t = threadIdx.x;
  float v[4];
  float mx = -INFINITY;
#pragma unroll
  for (int i = 0; i < 4; ++i) { v[i] = lm[i * 256 + t]; mx = fmaxf(mx, v[i]); }
  red[t] = mx;
  __syncthreads();
  for (int s = 128; s > 0; s >>= 1) {
    if (t < s) red[t] = fmaxf(red[t], red[t + s]);
    __syncthreads();
  }
  mx = red[0];
  __syncthreads();
  float sum = 0.f;
#pragma unroll
  for (int i = 0; i < 4; ++i) { v[i] -= mx; sum += expf(v[i]); }
  red[t] = sum;
  __syncthreads();
  for (int s = 128; s > 0; s >>= 1) {
    if (t < s) red[t] += red[t + s];
    __syncthreads();
  }
  const float l = logf(red[0]);
#pragma unroll
  for (int i = 0; i < 4; ++i) lp[i * 256 + t] = v[i] - l;
}

// Exact 3-way bf16 split of Y = [C | C^2], single interleaved blob:
// yb[((tile*3 + part)*64 + lane)] (bf16x8, 16 B) where tile = s*64 + c,
// holds Y[n = c*16+(lane&15)][k = s*32+(lane>>4)*8 ..+7], part 0=h,1=m,2=l.
__global__ void prep_y(const float* __restrict__ centroids, bf16x8* __restrict__ yb) {
  const int tid = blockIdx.x * 256 + threadIdx.x;  // 0..16383
  const int l = tid & 63;
  const int c = (tid >> 6) & 63;
  const int s = tid >> 12;
  const int n = c * 16 + (l & 15);
  const int k0 = s * 32 + (l >> 4) * 8;
  bf16x8 h, mid, lo;
#pragma unroll
  for (int j = 0; j < 8; ++j) {
    const int k = k0 + j;
    float y;
    if (k < 64) {
      y = centroids[n * M_F + k];
    } else {
      const float cc = centroids[n * M_F + (k - 64)];
      y = cc * cc;
    }
    const short hh = f2bf(y);
    const float r1 = y - bf2f(hh);        // exact
    const short mm = f2bf(r1);
    const float r2 = r1 - bf2f(mm);       // exact
    h[j] = hh;
    mid[j] = mm;
    lo[j] = f2bf(r2);                     // exact
  }
  const int tile = s * 64 + c;
  yb[(size_t)(tile * 3 + 0) * 64 + l] = h;
  yb[(size_t)(tile * 3 + 1) * 64 + l] = mid;
  yb[(size_t)(tile * 3 + 2) * 64 + l] = lo;
}

// 256 threads = 4 waves. Wave w: c-tiles w*16..w*16+15 (cols w*256..+255). 2048 blocks.
// (256,4): 4 blocks/CU for cross-block epilogue/K-loop overlap; PF=2 ring + single
// blob keeps the working set ~125 regs. Ring refills CROSS s-boundaries (one load
// burst per kernel, not per s-step).
__global__ __launch_bounds__(256, 4) void rmm_main(
    const float* __restrict__ samples, const float* __restrict__ mask,
    const float* __restrict__ sd, const float* __restrict__ lp_g,
    const bf16x8* __restrict__ yb_g, float* __restrict__ out) {
  __shared__ float xs[R_B * LDX];   // X fp32 [row][k]: k<64 -> -2uA, k>=64 -> u
  __shared__ float lp_s[N_C];
  __shared__ float ad_s[R_B];
  __shared__ float red_s[R_B * 4];

  const int t = threadIdx.x;
  const int b0 = blockIdx.x * R_B;
  const int w = t >> 6;
  const int l = t & 63;
  const int m = l & 15;
  const int q = l >> 4;

  *(float4*)(lp_s + (t << 2)) = *(const float4*)(lp_g + (t << 2));

  // ---- build X rows, A_d = sum((m*A)^2) ----
  {
    const int r = t >> 4;
    const int j4 = (t & 15) << 2;
    const float4 s4 = *(const float4*)(samples + (size_t)(b0 + r) * M_F + j4);
    const float4 m4 = *(const float4*)(mask + (size_t)(b0 + r) * M_F + j4);
    const float4 d4 = *(const float4*)(sd + j4);
    const float sa[4] = {s4.x, s4.y, s4.z, s4.w};
    const float ma[4] = {m4.x, m4.y, m4.z, m4.w};
    const float da[4] = {d4.x, d4.y, d4.z, d4.w};
    float ad = 0.f;
#pragma unroll
    for (int k = 0; k < 4; ++k) {
      const float mm = ma[k] / da[k];
      const float uu = mm * mm;
      const float mA = mm * sa[k];
      ad = fmaf(mA, mA, ad);
      xs[r * LDX + j4 + k] = -2.0f * (uu * sa[k]);
      xs[r * LDX + 64 + j4 + k] = uu;
    }
#pragma unroll
    for (int off = 1; off < 16; off <<= 1) ad += __shfl_xor(ad, off, 64);
    if ((t & 15) == 0) ad_s[r] = ad;
  }

  f32x4 acc[16];
#pragma unroll
  for (int c = 0; c < 16; ++c) acc[c] = (f32x4){0.f, 0.f, 0.f, 0.f};

  __syncthreads();

  // lane-offset base pointer; tile g for (s,c) is g = s*64 + w*16 + c
  const bf16x8* yb = yb_g + l;

  // ---- preload ring: tiles (s=0, c=0..PF-1) — the ONLY load burst ----
  bf16x8 Bh[PF], Bm[PF], Bl[PF];
#pragma unroll
  for (int p = 0; p < PF; ++p) {
    const int g = w * 16 + p;
    Bh[p] = yb[(size_t)(g * 3 + 0) * 64];
    Bm[p] = yb[(size_t)(g * 3 + 1) * 64];
    Bl[p] = yb[(size_t)(g * 3 + 2) * 64];
  }

  bf16x8 ah, am, al;

  // ---- K loop: 4 s-steps x 16 c-tiles, ring refills cross the s boundary ----
#pragma unroll 1
  for (int s = 0; s < 4; ++s) {
    // A fragment split for this s (from LDS; overlaps in-flight ring loads)
    {
      const float* xp = &xs[m * LDX + s * 32 + q * 8];
      float av[8];
      *(float4*)&av[0] = *(const float4*)xp;
      *(float4*)&av[4] = *(const float4*)(xp + 4);
      split3(av, ah, am, al);
    }

#pragma unroll
    for (int c = 0; c < 16; ++c) {
      const int cur = (s * 16 + c) & (PF - 1);
      const bf16x8 bh = Bh[cur], bm = Bm[cur], bl = Bl[cur];
      // refill with tile (linear tc + PF), crossing into s+1 when needed
      const int tcr = s * 16 + c + PF;
      if (tcr < 64) {
        const int gr = (tcr >> 4) * 64 + w * 16 + (tcr & 15);
        Bh[cur] = yb[(size_t)(gr * 3 + 0) * 64];
        Bm[cur] = yb[(size_t)(gr * 3 + 1) * 64];
        Bl[cur] = yb[(size_t)(gr * 3 + 2) * 64];
      }
      // small -> large; only Xl*Yl dropped (order identical to R3/R8)
      acc[c] = __builtin_amdgcn_mfma_f32_16x16x32_bf16(am, bl, acc[c], 0, 0, 0);
      acc[c] = __builtin_amdgcn_mfma_f32_16x16x32_bf16(al, bm, acc[c], 0, 0, 0);
      acc[c] = __builtin_amdgcn_mfma_f32_16x16x32_bf16(ah, bl, acc[c], 0, 0, 0);
      acc[c] = __builtin_amdgcn_mfma_f32_16x16x32_bf16(am, bm, acc[c], 0, 0, 0);
      acc[c] = __builtin_amdgcn_mfma_f32_16x16x32_bf16(al, bh, acc[c], 0, 0, 0);
      acc[c] = __builtin_amdgcn_mfma_f32_16x16x32_bf16(ah, bm, acc[c], 0, 0, 0);
      acc[c] = __builtin_amdgcn_mfma_f32_16x16x32_bf16(am, bh, acc[c], 0, 0, 0);
      acc[c] = __builtin_amdgcn_mfma_f32_16x16x32_bf16(ah, bh, acc[c], 0, 0, 0);
    }
  }

  // ---- epilogue: C/D layout row = q*4+g, col = w*256 + c*16 + m ----
  float adv[4];
#pragma unroll
  for (int g = 0; g < 4; ++g) adv[g] = ad_s[q * 4 + g];
  float lpv[16];
#pragma unroll
  for (int c = 0; c < 16; ++c) lpv[c] = lp_s[w * 256 + c * 16 + m];

#pragma unroll
  for (int c = 0; c < 16; ++c)
#pragma unroll
    for (int g = 0; g < 4; ++g) {
      const float dist = fmaxf(adv[g] + acc[c][g], 0.0f);
      acc[c][g] = lpv[c] - 0.5f * dist;
    }

  float mx[4];
#pragma unroll
  for (int g = 0; g < 4; ++g) {
    float v = acc[0][g];
#pragma unroll
    for (int c = 1; c < 16; ++c) v = fmaxf(v, acc[c][g]);
#pragma unroll
    for (int off = 1; off < 16; off <<= 1) v = fmaxf(v, __shfl_xor(v, off, 64));
    mx[g] = v;
  }
  if (m == 0) {
#pragma unroll
    for (int g = 0; g < 4; ++g) red_s[(q * 4 + g) * 4 + w] = mx[g];
  }
  __syncthreads();
#pragma unroll
  for (int g = 0; g < 4; ++g) {
    const float4 rv = *(const float4*)(&red_s[(q * 4 + g) * 4]);
    mx[g] = fmaxf(fmaxf(rv.x, rv.y), fmaxf(rv.z, rv.w));
  }
  __syncthreads();

  float sm[4];
#pragma unroll
  for (int g = 0; g < 4; ++g) {
    float ssum = 0.f;
#pragma unroll
    for (int c = 0; c < 16; ++c) {
      const float e = __expf(acc[c][g] - mx[g]);
      acc[c][g] = e;
      ssum += e;
    }
#pragma unroll
    for (int off = 1; off < 16; off <<= 1) ssum += __shfl_xor(ssum, off, 64);
    sm[g] = ssum;
  }
  if (m == 0) {
#pragma unroll
    for (int g = 0; g < 4; ++g) red_s[(q * 4 + g) * 4 + w] = sm[g];
  }
  __syncthreads();
#pragma unroll
  for (int g = 0; g < 4; ++g) {
    const float4 rv = *(const float4*)(&red_s[(q * 4 + g) * 4]);
    sm[g] = (rv.x + rv.y) + (rv.z + rv.w);
  }
  __syncthreads();

  float thr[4], qs[4];
#pragma unroll
  for (int g = 0; g < 4; ++g) {
    const float S1 = sm[g];
    thr[g] = 0.05f * (1.0f / S1);
    float s2 = 0.f;
#pragma unroll
    for (int c = 0; c < 16; ++c) {
      const float p = acc[c][g] / S1;   // IEEE div, matches np decision band
      acc[c][g] = p;
      s2 += (p > thr[g]) ? p : 0.0f;
    }
#pragma unroll
    for (int off = 1; off < 16; off <<= 1) s2 += __shfl_xor(s2, off, 64);
    qs[g] = s2;
  }
  if (m == 0) {
#pragma unroll
    for (int g = 0; g < 4; ++g) red_s[(q * 4 + g) * 4 + w] = qs[g];
  }
  __syncthreads();
#pragma unroll
  for (int g = 0; g < 4; ++g) {
    const float4 rv = *(const float4*)(&red_s[(q * 4 + g) * 4]);
    qs[g] = (rv.x + rv.y) + (rv.z + rv.w);
  }

  const size_t colbase = (size_t)(w * 256 + m);
#pragma unroll
  for (int g = 0; g < 4; ++g) {
    const float rq = 1.0f / qs[g];
    float* orow = out + (size_t)(b0 + q * 4 + g) * N_C + colbase;
    float* lrow = orow + (size_t)B_R * N_C;
#pragma unroll
    for (int c = 0; c < 16; ++c) {
      const float p = acc[c][g];
      const float pf = (p > thr[g]) ? (p * rq) : 0.0f;
      orow[c * 16] = pf;
      lrow[c * 16] = __logf(pf + 1e-20f);
    }
  }
}

extern "C" void kernel_launch(void* const* d_in, const int* in_sizes, int n_in,
                              void* d_out, int out_size, void* d_ws, size_t ws_size,
                              hipStream_t stream) {
  const float* samples   = (const float*)d_in[0];
  const float* mask      = (const float*)d_in[1];
  const float* centroids = (const float*)d_in[2];
  const float* sd        = (const float*)d_in[3];
  const float* lm        = (const float*)d_in[4];
  float* out = (float*)d_out;

  char* ws = (char*)d_ws;
  float* lp  = (float*)ws;                 // 4 KB
  bf16x8* yb = (bf16x8*)(ws + 4096);       // 768 KB interleaved split-Y blob

  logprior_kernel<<<1, 256, 0, stream>>>(lm, lp);
  prep_y<<<64, 256, 0, stream>>>(centroids, yb);
  rmm_main<<<B_R / R_B, 256, 0, stream>>>(samples, mask, sd, lp, yb, out);
}

// Round 11
// 339.180 us; speedup vs baseline: 1.0438x; 1.0438x over previous
//
#include <hip/hip_runtime.h>
#include <math.h>

#define N_C 1024
#define M_F 64
#define B_R 32768
#define R_B 16       // sample rows per block
#define LDX 132      // padded fp32 leading dim for X in LDS
#define PF  4        // ring depth; MUST divide 16 (slot == linear tile % PF)

typedef short bf16x8 __attribute__((ext_vector_type(8)));
typedef float f32x4 __attribute__((ext_vector_type(4)));
typedef unsigned int uint4v __attribute__((ext_vector_type(4)));

__device__ __forceinline__ short f2bf(float x) {
  unsigned b = __float_as_uint(x);
  b += 0x7fffu + ((b >> 16) & 1u);   // RTNE (finite inputs only)
  return (short)(b >> 16);
}
__device__ __forceinline__ float bf2f(short h) {
  return __uint_as_float(((unsigned)(unsigned short)h) << 16);
}

// Exact truncation-based 3-way split (h+m+l == x exactly); bit-ops only.
__device__ __forceinline__ void split3(const float* f, bf16x8& h, bf16x8& m, bf16x8& l) {
  uint4v hp, mp, lp;
#pragma unroll
  for (int i = 0; i < 4; ++i) {
    const unsigned b0 = __float_as_uint(f[2 * i]);
    const unsigned b1 = __float_as_uint(f[2 * i + 1]);
    const unsigned h0 = b0 & 0xFFFF0000u, h1 = b1 & 0xFFFF0000u;
    const float r0 = f[2 * i] - __uint_as_float(h0);       // exact
    const float r1 = f[2 * i + 1] - __uint_as_float(h1);   // exact
    hp[i] = (b0 >> 16) | h1;
    const unsigned rb0 = __float_as_uint(r0), rb1 = __float_as_uint(r1);
    const unsigned m0 = rb0 & 0xFFFF0000u, m1 = rb1 & 0xFFFF0000u;
    const float s0 = r0 - __uint_as_float(m0);             // exact
    const float s1 = r1 - __uint_as_float(m1);             // exact
    mp[i] = (rb0 >> 16) | m1;
    lp[i] = (__float_as_uint(s0) >> 16) | (__float_as_uint(s1) & 0xFFFF0000u);
  }
  h = __builtin_bit_cast(bf16x8, hp);
  m = __builtin_bit_cast(bf16x8, mp);
  l = __builtin_bit_cast(bf16x8, lp);
}

__global__ void logprior_kernel(const float* __restrict__ lm, float* __restrict__ lp) {
  __shared__ float red[256];
  const int t = threadIdx.x;
  float v[4];
  float mx = -INFINITY;
#pragma unroll
  for (int i = 0; i < 4; ++i) { v[i] = lm[i * 256 + t]; mx = fmaxf(mx, v[i]); }
  red[t] = mx;
  __syncthreads();
  for (int s = 128; s > 0; s >>= 1) {
    if (t < s) red[t] = fmaxf(red[t], red[t + s]);
    __syncthreads();
  }
  mx = red[0];
  __syncthreads();
  float sum = 0.f;
#pragma unroll
  for (int i = 0; i < 4; ++i) { v[i] -= mx; sum += expf(v[i]); }
  red[t] = sum;
  __syncthreads();
  for (int s = 128; s > 0; s >>= 1) {
    if (t < s) red[t] += red[t + s];
    __syncthreads();
  }
  const float l = logf(red[0]);
#pragma unroll
  for (int i = 0; i < 4; ++i) lp[i * 256 + t] = v[i] - l;
}

// Exact 3-way bf16 split of Y = [C | C^2], single interleaved blob:
// yb[((tile*3 + part)*64 + lane)] (bf16x8) where tile = s*64 + c,
// holds Y[n = c*16+(lane&15)][k = s*32+(lane>>4)*8 ..+7], part 0=h,1=m,2=l.
__global__ void prep_y(const float* __restrict__ centroids, bf16x8* __restrict__ yb) {
  const int tid = blockIdx.x * 256 + threadIdx.x;  // 0..16383
  const int l = tid & 63;
  const int c = (tid >> 6) & 63;
  const int s = tid >> 12;
  const int n = c * 16 + (l & 15);
  const int k0 = s * 32 + (l >> 4) * 8;
  bf16x8 h, mid, lo;
#pragma unroll
  for (int j = 0; j < 8; ++j) {
    const int k = k0 + j;
    float y;
    if (k < 64) {
      y = centroids[n * M_F + k];
    } else {
      const float cc = centroids[n * M_F + (k - 64)];
      y = cc * cc;
    }
    const short hh = f2bf(y);
    const float r1 = y - bf2f(hh);        // exact
    const short mm = f2bf(r1);
    const float r2 = r1 - bf2f(mm);       // exact
    h[j] = hh;
    mid[j] = mm;
    lo[j] = f2bf(r2);                     // exact
  }
  const int tile = s * 64 + c;
  yb[(size_t)(tile * 3 + 0) * 64 + l] = h;
  yb[(size_t)(tile * 3 + 1) * 64 + l] = mid;
  yb[(size_t)(tile * 3 + 2) * 64 + l] = lo;
}

// 256 threads = 4 waves. Wave w: c-tiles w*16..w*16+15. 2048 blocks, 3 blocks/CU.
// c-pairs with interleaved MFMA chains; PF=4 ring (divides 16 -> slot index
// (2j)%4 equals linear-tile%4 across s-boundaries), refill-after-use.
__global__ __launch_bounds__(256, 3) void rmm_main(
    const float* __restrict__ samples, const float* __restrict__ mask,
    const float* __restrict__ sd, const float* __restrict__ lp_g,
    const bf16x8* __restrict__ yb_g, float* __restrict__ out) {
  __shared__ float xs[R_B * LDX];   // X fp32 [row][k]: k<64 -> -2uA, k>=64 -> u
  __shared__ float lp_s[N_C];
  __shared__ float ad_s[R_B];
  __shared__ float red_s[R_B * 4];

  const int t = threadIdx.x;
  const int b0 = blockIdx.x * R_B;
  const int w = t >> 6;
  const int l = t & 63;
  const int m = l & 15;
  const int q = l >> 4;

  *(float4*)(lp_s + (t << 2)) = *(const float4*)(lp_g + (t << 2));

  // ---- build X rows, A_d = sum((m*A)^2) ----
  {
    const int r = t >> 4;
    const int j4 = (t & 15) << 2;
    const float4 s4 = *(const float4*)(samples + (size_t)(b0 + r) * M_F + j4);
    const float4 m4 = *(const float4*)(mask + (size_t)(b0 + r) * M_F + j4);
    const float4 d4 = *(const float4*)(sd + j4);
    const float sa[4] = {s4.x, s4.y, s4.z, s4.w};
    const float ma[4] = {m4.x, m4.y, m4.z, m4.w};
    const float da[4] = {d4.x, d4.y, d4.z, d4.w};
    float ad = 0.f;
#pragma unroll
    for (int k = 0; k < 4; ++k) {
      const float mm = ma[k] / da[k];
      const float uu = mm * mm;
      const float mA = mm * sa[k];
      ad = fmaf(mA, mA, ad);
      xs[r * LDX + j4 + k] = -2.0f * (uu * sa[k]);
      xs[r * LDX + 64 + j4 + k] = uu;
    }
#pragma unroll
    for (int off = 1; off < 16; off <<= 1) ad += __shfl_xor(ad, off, 64);
    if ((t & 15) == 0) ad_s[r] = ad;
  }

  f32x4 acc[16];
#pragma unroll
  for (int c = 0; c < 16; ++c) acc[c] = (f32x4){0.f, 0.f, 0.f, 0.f};

  __syncthreads();

  const bf16x8* yb = yb_g + l;

  // ---- preload ring: linear tiles 0..PF-1 (within s=0) ----
  bf16x8 Bh[PF], Bm[PF], Bl[PF];
#pragma unroll
  for (int p = 0; p < PF; ++p) {
    const int g = w * 16 + p;
    Bh[p] = yb[(size_t)(g * 3 + 0) * 64];
    Bm[p] = yb[(size_t)(g * 3 + 1) * 64];
    Bl[p] = yb[(size_t)(g * 3 + 2) * 64];
  }

  bf16x8 ah, am, al;

  // split order (small -> large); 0=h,1=m,2=l; only Xl*Yl dropped
  const int sx[8] = {1, 2, 0, 1, 2, 0, 1, 0};
  const int sy[8] = {2, 1, 2, 1, 0, 1, 0, 0};

  // ---- K loop: 4 s-steps x 8 c-pairs; 2 interleaved MFMA chains per pair ----
#pragma unroll 1
  for (int s = 0; s < 4; ++s) {
    {
      const float* xp = &xs[m * LDX + s * 32 + q * 8];
      float av[8];
      *(float4*)&av[0] = *(const float4*)xp;
      *(float4*)&av[4] = *(const float4*)(xp + 4);
      split3(av, ah, am, al);
    }

#pragma unroll
    for (int j = 0; j < 8; ++j) {
      const int c0 = 2 * j, c1 = 2 * j + 1;
      const int s0 = (2 * j) & (PF - 1), s1 = (2 * j + 1) & (PF - 1);

      // 16 MFMAs, alternating between the two accumulator chains
#pragma unroll
      for (int sp = 0; sp < 8; ++sp) {
        const bf16x8 a = (sx[sp] == 0) ? ah : ((sx[sp] == 1) ? am : al);
        const bf16x8 b0 = (sy[sp] == 0) ? Bh[s0] : ((sy[sp] == 1) ? Bm[s0] : Bl[s0]);
        const bf16x8 b1 = (sy[sp] == 0) ? Bh[s1] : ((sy[sp] == 1) ? Bm[s1] : Bl[s1]);
        acc[c0] = __builtin_amdgcn_mfma_f32_16x16x32_bf16(a, b0, acc[c0], 0, 0, 0);
        acc[c1] = __builtin_amdgcn_mfma_f32_16x16x32_bf16(a, b1, acc[c1], 0, 0, 0);
      }

      // refill-after-use with linear tile tc + PF (slot == tc % PF, boundary-safe)
      const int tc0 = s * 16 + 2 * j + PF;
      if (tc0 < 64) {
        const int g0 = (tc0 >> 4) * 64 + w * 16 + (tc0 & 15);
        Bh[s0] = yb[(size_t)(g0 * 3 + 0) * 64];
        Bm[s0] = yb[(size_t)(g0 * 3 + 1) * 64];
        Bl[s0] = yb[(size_t)(g0 * 3 + 2) * 64];
      }
      const int tc1 = tc0 + 1;
      if (tc1 < 64) {
        const int g1 = (tc1 >> 4) * 64 + w * 16 + (tc1 & 15);
        Bh[s1] = yb[(size_t)(g1 * 3 + 0) * 64];
        Bm[s1] = yb[(size_t)(g1 * 3 + 1) * 64];
        Bl[s1] = yb[(size_t)(g1 * 3 + 2) * 64];
      }
    }
  }

  // ---- epilogue: C/D layout row = q*4+g, col = w*256 + c*16 + m ----
  float adv[4];
#pragma unroll
  for (int g = 0; g < 4; ++g) adv[g] = ad_s[q * 4 + g];
  float lpv[16];
#pragma unroll
  for (int c = 0; c < 16; ++c) lpv[c] = lp_s[w * 256 + c * 16 + m];

#pragma unroll
  for (int c = 0; c < 16; ++c)
#pragma unroll
    for (int g = 0; g < 4; ++g) {
      const float dist = fmaxf(adv[g] + acc[c][g], 0.0f);
      acc[c][g] = lpv[c] - 0.5f * dist;
    }

  float mx[4];
#pragma unroll
  for (int g = 0; g < 4; ++g) {
    float v = acc[0][g];
#pragma unroll
    for (int c = 1; c < 16; ++c) v = fmaxf(v, acc[c][g]);
#pragma unroll
    for (int off = 1; off < 16; off <<= 1) v = fmaxf(v, __shfl_xor(v, off, 64));
    mx[g] = v;
  }
  if (m == 0) {
#pragma unroll
    for (int g = 0; g < 4; ++g) red_s[(q * 4 + g) * 4 + w] = mx[g];
  }
  __syncthreads();
#pragma unroll
  for (int g = 0; g < 4; ++g) {
    const float4 rv = *(const float4*)(&red_s[(q * 4 + g) * 4]);
    mx[g] = fmaxf(fmaxf(rv.x, rv.y), fmaxf(rv.z, rv.w));
  }
  __syncthreads();

  float sm[4];
#pragma unroll
  for (int g = 0; g < 4; ++g) {
    float ssum = 0.f;
#pragma unroll
    for (int c = 0; c < 16; ++c) {
      const float e = __expf(acc[c][g] - mx[g]);
      acc[c][g] = e;
      ssum += e;
    }
#pragma unroll
    for (int off = 1; off < 16; off <<= 1) ssum += __shfl_xor(ssum, off, 64);
    sm[g] = ssum;
  }
  if (m == 0) {
#pragma unroll
    for (int g = 0; g < 4; ++g) red_s[(q * 4 + g) * 4 + w] = sm[g];
  }
  __syncthreads();
#pragma unroll
  for (int g = 0; g < 4; ++g) {
    const float4 rv = *(const float4*)(&red_s[(q * 4 + g) * 4]);
    sm[g] = (rv.x + rv.y) + (rv.z + rv.w);
  }
  __syncthreads();

  float thr[4], qs[4];
#pragma unroll
  for (int g = 0; g < 4; ++g) {
    const float S1 = sm[g];
    thr[g] = 0.05f * (1.0f / S1);
    float s2 = 0.f;
#pragma unroll
    for (int c = 0; c < 16; ++c) {
      const float p = acc[c][g] / S1;   // IEEE div, matches np decision band
      acc[c][g] = p;
      s2 += (p > thr[g]) ? p : 0.0f;
    }
#pragma unroll
    for (int off = 1; off < 16; off <<= 1) s2 += __shfl_xor(s2, off, 64);
    qs[g] = s2;
  }
  if (m == 0) {
#pragma unroll
    for (int g = 0; g < 4; ++g) red_s[(q * 4 + g) * 4 + w] = qs[g];
  }
  __syncthreads();
#pragma unroll
  for (int g = 0; g < 4; ++g) {
    const float4 rv = *(const float4*)(&red_s[(q * 4 + g) * 4]);
    qs[g] = (rv.x + rv.y) + (rv.z + rv.w);
  }

  const size_t colbase = (size_t)(w * 256 + m);
#pragma unroll
  for (int g = 0; g < 4; ++g) {
    const float rq = 1.0f / qs[g];
    float* orow = out + (size_t)(b0 + q * 4 + g) * N_C + colbase;
    float* lrow = orow + (size_t)B_R * N_C;
#pragma unroll
    for (int c = 0; c < 16; ++c) {
      const float p = acc[c][g];
      const float pf = (p > thr[g]) ? (p * rq) : 0.0f;
      orow[c * 16] = pf;
      lrow[c * 16] = __logf(pf + 1e-20f);
    }
  }
}

extern "C" void kernel_launch(void* const* d_in, const int* in_sizes, int n_in,
                              void* d_out, int out_size, void* d_ws, size_t ws_size,
                              hipStream_t stream) {
  const float* samples   = (const float*)d_in[0];
  const float* mask      = (const float*)d_in[1];
  const float* centroids = (const float*)d_in[2];
  const float* sd        = (const float*)d_in[3];
  const float* lm        = (const float*)d_in[4];
  float* out = (float*)d_out;

  char* ws = (char*)d_ws;
  float* lp  = (float*)ws;                 // 4 KB
  bf16x8* yb = (bf16x8*)(ws + 4096);       // 768 KB interleaved split-Y blob

  logprior_kernel<<<1, 256, 0, stream>>>(lm, lp);
  prep_y<<<64, 256, 0, stream>>>(centroids, yb);
  rmm_main<<<B_R / R_B, 256, 0, stream>>>(samples, mask, sd, lp, yb, out);
}